// Round 4
// baseline (616.473 us; speedup 1.0000x reference)
//
#include <hip/hip_runtime.h>
#include <math.h>

#define B_  8
#define T_  2048
#define D_  1024
#define E_  8
#define FF_ 4096
#define N_  64            // B*E rows through the FFN
#define BT_ (B_*T_)
#define NBLK 512

// ---- d_out regions (float offsets); all dead before combine overwrites ----
#define LPART_F  0u           // [8][BT][8]      4 MB   (logit partials)
#define SPART_F  1048576u     // [32][64][1024]  8 MB   (slot partials)
#define G1PART_F 3145728u     // [16][64][4096] 16 MB   (gemm1 partials)
#define G2PART_F 7340032u     // [64][64][1024] 16 MB   (gemm2 partials)

// Monotonic grid barrier: all 512 blocks co-resident (LDS 36.9KB*2=74KB<160,
// launch_bounds caps VGPR for 2 blocks/CU). threadfence = agent-scope
// release/acquire (buffer_wbl2/buffer_inv on gfx950) -> cross-XCD visibility.
__device__ __forceinline__ void gsync(int* bar, int target)
{
    __syncthreads();                       // drains each wave's vmcnt first
    if (threadIdx.x == 0) {
        __threadfence();                   // release: L2 writeback
        atomicAdd(bar, 1);
        int guard = 0;
        while (atomicAdd(bar, 0) < target) {
            __builtin_amdgcn_s_sleep(32);
            if (++guard > (1 << 24)) break;   // safety valve (never hit if resident)
        }
        __threadfence();                   // acquire: L1/L2 invalidate
    }
    __syncthreads();
}

// k-split GEMM tile, KT=64. Block tile 64 rows x 128 cols, 256 threads:
// thread = (rg=tid>>5: 8 rows, cg=tid&31: 4 cols). acc = 8 x float4 (32 VGPR).
// A-tile staged in LDS (reads are half-wave broadcasts); W coalesced b128.
template<int K, int F>
__device__ __forceinline__ void gemm_phase(
    const float* __restrict__ A, const float* __restrict__ W,
    float* __restrict__ part, float* As, int fc, int kc)
{
    const int tid = threadIdx.x;
    const int rg = tid >> 5, cg = tid & 31;
    const int f0 = fc * 128 + cg * 4;
    const int k0 = kc * 64;

    #pragma unroll
    for (int i = 0; i < 4; ++i) {                 // 1024 float4, coalesced
        int idx = i * 256 + tid;
        int row = idx >> 4, kq = idx & 15;
        *(float4*)&As[row * 64 + kq * 4] =
            *(const float4*)&A[(size_t)row * K + k0 + kq * 4];
    }
    __syncthreads();

    float4 acc[8];
    #pragma unroll
    for (int r = 0; r < 8; ++r) acc[r] = make_float4(0.f, 0.f, 0.f, 0.f);

    #pragma unroll 2
    for (int kq = 0; kq < 16; ++kq) {
        const float* wr = &W[(size_t)(k0 + kq * 4) * F + f0];
        const float4 w0 = *(const float4*)&wr[0];
        const float4 w1 = *(const float4*)&wr[(size_t)F];
        const float4 w2 = *(const float4*)&wr[(size_t)2 * F];
        const float4 w3 = *(const float4*)&wr[(size_t)3 * F];
        #pragma unroll
        for (int r = 0; r < 8; ++r) {
            const float4 a = *(const float4*)&As[(rg * 8 + r) * 64 + kq * 4];
            acc[r].x += a.x*w0.x + a.y*w1.x + a.z*w2.x + a.w*w3.x;
            acc[r].y += a.x*w0.y + a.y*w1.y + a.z*w2.y + a.w*w3.y;
            acc[r].z += a.x*w0.z + a.y*w1.z + a.z*w2.z + a.w*w3.z;
            acc[r].w += a.x*w0.w + a.y*w1.w + a.z*w2.w + a.w*w3.w;
        }
    }
    float* pb = &part[(size_t)kc * N_ * F];
    #pragma unroll
    for (int r = 0; r < 8; ++r)
        *(float4*)&pb[(size_t)(rg * 8 + r) * F + f0] = acc[r];
}

__global__ __launch_bounds__(256, 2) void k_mega(
    const float* __restrict__ X, const float* __restrict__ Wg,
    const float* __restrict__ bg, const float* __restrict__ W1,
    const float* __restrict__ b1, const float* __restrict__ W2,
    const float* __restrict__ b2, float* __restrict__ outbuf,
    float* __restrict__ logits, float* __restrict__ sexp,
    float* __restrict__ slots, float* __restrict__ h,
    float* __restrict__ y, int* bar)
{
    __shared__ float lds[9216];          // 36 KB union: xt / wlds / As
    const int tid = threadIdx.x;
    const int vb  = blockIdx.x;

    // ----- P0: logit partials over a 128-d chunk (X pass 1) -----
    // vb -> (dchunk = vb>>6 in 0..7, btc = vb&63). Thread owns one token x 8e.
    {
        const int bt0 = (vb & 63) * 256;
        const int d0  = (vb >> 6) * 128;
        float acc[8];
        #pragma unroll
        for (int e = 0; e < 8; ++e) acc[e] = 0.f;

        for (int dt = 0; dt < 4; ++dt) {
            if (dt) __syncthreads();
            #pragma unroll
            for (int r = 0; r < 8; ++r) {
                int fi = r * 256 + tid;       // = token*8 + dj
                int token = fi >> 3, dj = fi & 7;
                const float4 v = *(const float4*)
                    &X[(size_t)(bt0 + token) * D_ + d0 + dt * 32 + dj * 4];
                *(float4*)&lds[token * 36 + dj * 4] = v;
            }
            __syncthreads();
            #pragma unroll
            for (int dj = 0; dj < 8; ++dj) {
                const float4 x4 = *(const float4*)&lds[tid * 36 + dj * 4];
                const int db = d0 + dt * 32 + dj * 4;      // block-uniform
                const float xv[4] = {x4.x, x4.y, x4.z, x4.w};
                #pragma unroll
                for (int rr = 0; rr < 4; ++rr) {
                    const float4 wlo = *(const float4*)&Wg[(size_t)(db + rr) * 8];
                    const float4 whi = *(const float4*)&Wg[(size_t)(db + rr) * 8 + 4];
                    acc[0] += xv[rr]*wlo.x; acc[1] += xv[rr]*wlo.y;
                    acc[2] += xv[rr]*wlo.z; acc[3] += xv[rr]*wlo.w;
                    acc[4] += xv[rr]*whi.x; acc[5] += xv[rr]*whi.y;
                    acc[6] += xv[rr]*whi.z; acc[7] += xv[rr]*whi.w;
                }
            }
        }
        float* pp = &outbuf[LPART_F + (size_t)(vb >> 6) * BT_ * E_
                            + (size_t)(bt0 + tid) * E_];
        *(float4*)&pp[0] = make_float4(acc[0], acc[1], acc[2], acc[3]);
        *(float4*)&pp[4] = make_float4(acc[4], acc[5], acc[6], acc[7]);
    }
    gsync(bar, NBLK);

    // ----- P1: merge logits + exp (UNNORMALIZED) + slot partials (X pass 2) -----
    // 256 active blocks: (ts = vb&31: 64-token slice, b = vb>>5).
    if (vb < 256) {
        const int ts = vb & 31, b = vb >> 5;
        const int t0 = ts * 64;
        float* wlds = lds;                       // 512 floats

        #pragma unroll
        for (int r = 0; r < 2; ++r) {
            int idx = r * 256 + tid;             // = t*8 + e
            int t = idx >> 3, e = idx & 7;
            float a = bg[e];
            #pragma unroll
            for (int dc = 0; dc < 8; ++dc)
                a += outbuf[LPART_F + (size_t)dc * BT_ * E_
                            + ((size_t)b * T_ + t0 + t) * E_ + e];
            logits[((size_t)b * T_ + t0 + t) * E_ + e] = a;
            wlds[idx] = expf(a);                 // unnormalized dispatch weight
        }
        __syncthreads();
        if (tid < 8) {                           // per-block sumexp partial
            float s = 0.f;
            for (int t = 0; t < 64; ++t) s += wlds[t * 8 + tid];
            sexp[(b * 32 + ts) * 8 + tid] = s;
        }

        float4 acc[8];
        #pragma unroll
        for (int e = 0; e < 8; ++e) acc[e] = make_float4(0.f, 0.f, 0.f, 0.f);

        const float* xb = &X[((size_t)b * T_ + t0) * D_ + tid * 4];
        #pragma unroll 8
        for (int t = 0; t < 64; ++t) {
            const float4 x4 = *(const float4*)&xb[(size_t)t * D_];
            const float4 wA = *(const float4*)&wlds[t * 8];       // broadcast
            const float4 wB = *(const float4*)&wlds[t * 8 + 4];   // broadcast
            const float w[8] = {wA.x, wA.y, wA.z, wA.w, wB.x, wB.y, wB.z, wB.w};
            #pragma unroll
            for (int e = 0; e < 8; ++e) {
                acc[e].x += x4.x * w[e];
                acc[e].y += x4.y * w[e];
                acc[e].z += x4.z * w[e];
                acc[e].w += x4.w * w[e];
            }
        }
        #pragma unroll
        for (int e = 0; e < 8; ++e)
            *(float4*)&outbuf[SPART_F + (size_t)ts * (N_ * D_)
                              + (size_t)(b * E_ + e) * D_ + tid * 4] = acc[e];
    }
    gsync(bar, 2 * NBLK);

    // ----- P2: reduce 32 slot partials, normalize by sumexp -----
    {
        const int gid = vb * 256 + tid;
        if (gid < 65536) {
            const int row = gid >> 10;           // b*8+e
            const int b = row >> 3, e = row & 7;
            float se = 0.f;
            #pragma unroll
            for (int t = 0; t < 32; ++t) se += sexp[(b * 32 + t) * 8 + e];
            float s = 0.f;
            #pragma unroll
            for (int p = 0; p < 32; ++p)
                s += outbuf[SPART_F + (size_t)p * (N_ * D_) + gid];
            slots[gid] = s / se;
        }
    }
    gsync(bar, 3 * NBLK);

    // ----- P3: GEMM1 partials (32 f-chunks x 16 k-chunks = 512 tiles) -----
    gemm_phase<1024, 4096>(slots, W1, &outbuf[G1PART_F], lds, vb >> 4, vb & 15);
    gsync(bar, 4 * NBLK);

    // ----- P4: reduce 16 + bias + SiLU -> h[64][4096] -----
    {
        #pragma unroll
        for (int s = 0; s < 2; ++s) {
            const int i = s * 131072 + vb * 256 + tid;
            float v = b1[i & (FF_ - 1)];
            #pragma unroll
            for (int p = 0; p < 16; ++p)
                v += outbuf[G1PART_F + (size_t)p * (N_ * FF_) + i];
            h[i] = v / (1.f + expf(-v));
        }
    }
    gsync(bar, 5 * NBLK);

    // ----- P5: GEMM2 partials (8 f-chunks x 64 k-chunks = 512 tiles) -----
    gemm_phase<4096, 1024>(h, W2, &outbuf[G2PART_F], lds, vb >> 6, vb & 63);
    gsync(bar, 6 * NBLK);

    // ----- P6: reduce 64 + bias -> y[64][1024] -----
    {
        const int gid = vb * 256 + tid;
        if (gid < 65536) {
            float v = b2[gid & (D_ - 1)];
            #pragma unroll
            for (int p = 0; p < 64; ++p)
                v += outbuf[G2PART_F + (size_t)p * (N_ * D_) + gid];
            y[gid] = v;
        }
    }
    gsync(bar, 7 * NBLK);

    // ----- P7: combine -> out (overwrites all partial regions) -----
    {
        float* wlds = lds;
        #pragma unroll
        for (int s = 0; s < 2; ++s) {
            const int cb = vb * 2 + s;           // 1024 logical tiles
            const int dc = cb & 3, tc = (cb >> 2) & 31, b = cb >> 7;
            const int t0 = tc * 64;

            __syncthreads();                     // protect wlds reuse
            if (tid < 64) {
                const float* lp = &logits[((size_t)b * T_ + t0 + tid) * E_];
                float ex[8]; float sm = 0.f;
                #pragma unroll
                for (int i = 0; i < 8; ++i) { ex[i] = expf(lp[i]); sm += ex[i]; }
                const float invs = 1.f / sm;
                #pragma unroll
                for (int i = 0; i < 8; ++i) wlds[tid * 8 + i] = ex[i] * invs;
            }
            __syncthreads();

            const int d = dc * 256 + tid;
            float yv[8];
            #pragma unroll
            for (int e = 0; e < 8; ++e) yv[e] = y[(size_t)(b * E_ + e) * D_ + d];

            for (int t = 0; t < 64; ++t) {
                const float4 wA = *(const float4*)&wlds[t * 8];
                const float4 wB = *(const float4*)&wlds[t * 8 + 4];
                const float acc = wA.x*yv[0] + wA.y*yv[1] + wA.z*yv[2] + wA.w*yv[3]
                                + wB.x*yv[4] + wB.y*yv[5] + wB.z*yv[6] + wB.w*yv[7];
                outbuf[((size_t)b * T_ + t0 + t) * D_ + d] = acc;
            }
        }
    }
}

// ---------------------------------------------------------------------------
extern "C" void kernel_launch(void* const* d_in, const int* in_sizes, int n_in,
                              void* d_out, int out_size, void* d_ws, size_t ws_size,
                              hipStream_t stream)
{
    const float* X  = (const float*)d_in[0];
    const float* Wg = (const float*)d_in[1];
    const float* bg = (const float*)d_in[2];
    const float* W1 = (const float*)d_in[3];
    const float* b1 = (const float*)d_in[4];
    const float* W2 = (const float*)d_in[5];
    const float* b2 = (const float*)d_in[6];
    float* out = (float*)d_out;

    // ws layout (fp32), ~2.1 MB
    float* wsf    = (float*)d_ws;
    int*   bar    = (int*)d_ws;                 // barrier counter (cacheline 0)
    float* logits = wsf + 64;                   // 131072
    float* sexp   = logits + BT_ * E_;          // 2048 (32 slices x 8 b x 8 e)
    float* slots  = sexp + 2048;                // 65536
    float* h      = slots + N_ * D_;            // 262144
    float* y      = h + N_ * FF_;               // 65536

    hipMemsetAsync(d_ws, 0, 256, stream);
    hipLaunchKernelGGL(k_mega, dim3(NBLK), dim3(256), 0, stream,
                       X, Wg, bg, W1, b1, W2, b2, out,
                       logits, sexp, slots, h, y, bar);
}

// Round 5
// 574.230 us; speedup vs baseline: 1.0736x; 1.0736x over previous
//
#include <hip/hip_runtime.h>
#include <math.h>

#define B_  8
#define T_  2048
#define D_  1024
#define E_  8
#define FF_ 4096
#define N_  64            // B*E rows through the FFN
#define BT_ (B_*T_)
#define NBLK 512

// ---- d_out regions (float offsets); all dead before combine overwrites ----
#define LPART_F  0u           // [8][BT][8]      4 MB   (logit partials)
#define SPART_F  1048576u     // [32][64][1024]  8 MB   (slot partials)
#define G1PART_F 3145728u     // [8][64][4096]   8 MB   (gemm1 partials)
#define G2PART_F 5242880u     // [32][64][1024]  8 MB   (gemm2 partials)

// Grid barrier, all 512 blocks co-resident (LDS 36KB*2 <= 160KB, lb(256,2)).
// Arrival: one device-scope RMW per block. Poll: device-scope relaxed LOAD
// (NOT an RMW -- 512 concurrent RMW polls serialize at the coherence point;
// that was round-4's ~65us/barrier). threadfence pair = release/acquire
// across non-coherent per-XCD L2s.
__device__ __forceinline__ void gsync(int* bar, int target)
{
    __syncthreads();
    if (threadIdx.x == 0) {
        __threadfence();                   // release: drain + L2 writeback
        __hip_atomic_fetch_add(bar, 1, __ATOMIC_RELAXED,
                               __HIP_MEMORY_SCOPE_AGENT);
        int guard = 0;
        while (__hip_atomic_load(bar, __ATOMIC_RELAXED,
                                 __HIP_MEMORY_SCOPE_AGENT) < target) {
            __builtin_amdgcn_s_sleep(16);
            if (++guard > (1 << 22)) break;   // safety valve
        }
        __threadfence();                   // acquire: invalidate stale L1/L2
    }
    __syncthreads();
}

// k-split GEMM tile: 64 rows x 64 cols, KT=128, 256 threads.
// thread = (rg=tid>>4: 4 rows, cg=tid&15: 4 cols); acc = 4 x float4 = 16 VGPR.
// As padded to 132 floats/row: rows 0,4,8,.. land on distinct banks
// (132%32=4), so the 4-distinct-row broadcast read is conflict-free.
template<int K, int F>
__device__ __forceinline__ void gemm_phase(
    const float* __restrict__ A, const float* __restrict__ W,
    float* __restrict__ part, float* As, int fc, int kc)
{
    const int tid = threadIdx.x;
    const int rg = tid >> 4, cg = tid & 15;
    const int f0 = fc * 64 + cg * 4;
    const int k0 = kc * 128;

    #pragma unroll
    for (int i = 0; i < 8; ++i) {                 // 2048 float4, coalesced
        int idx = i * 256 + tid;
        int row = idx >> 5, kq = idx & 31;
        *(float4*)&As[row * 132 + kq * 4] =
            *(const float4*)&A[(size_t)row * K + k0 + kq * 4];
    }
    __syncthreads();

    float4 acc[4];
    #pragma unroll
    for (int r = 0; r < 4; ++r) acc[r] = make_float4(0.f, 0.f, 0.f, 0.f);

    #pragma unroll 2
    for (int kq = 0; kq < 32; ++kq) {
        const float* wr = &W[(size_t)(k0 + kq * 4) * F + f0];
        const float4 w0 = *(const float4*)&wr[0];
        const float4 w1 = *(const float4*)&wr[(size_t)F];
        const float4 w2 = *(const float4*)&wr[2 * (size_t)F];
        const float4 w3 = *(const float4*)&wr[3 * (size_t)F];
        #pragma unroll
        for (int r = 0; r < 4; ++r) {
            const float4 a = *(const float4*)&As[(rg * 4 + r) * 132 + kq * 4];
            acc[r].x += a.x*w0.x + a.y*w1.x + a.z*w2.x + a.w*w3.x;
            acc[r].y += a.x*w0.y + a.y*w1.y + a.z*w2.y + a.w*w3.y;
            acc[r].z += a.x*w0.z + a.y*w1.z + a.z*w2.z + a.w*w3.z;
            acc[r].w += a.x*w0.w + a.y*w1.w + a.z*w2.w + a.w*w3.w;
        }
    }
    float* pb = &part[(size_t)kc * (N_ * F)];
    #pragma unroll
    for (int r = 0; r < 4; ++r)
        *(float4*)&pb[(size_t)(rg * 4 + r) * F + f0] = acc[r];
}

__global__ __launch_bounds__(256, 2) void k_mega(
    const float* __restrict__ X, const float* __restrict__ Wg,
    const float* __restrict__ bg, const float* __restrict__ W1,
    const float* __restrict__ b1, const float* __restrict__ W2,
    const float* __restrict__ b2, float* __restrict__ outbuf,
    float* __restrict__ logits, float* __restrict__ sexp,
    float* __restrict__ slots, float* __restrict__ h,
    float* __restrict__ y, int* bar)
{
    __shared__ float lds[9216];          // 36 KB union: xt / wlds / As
    const int tid = threadIdx.x;
    const int vb  = blockIdx.x;

    // ----- P0: logit partials over a 128-d chunk (X pass 1) -----
    {
        const int bt0 = (vb & 63) * 256;
        const int d0  = (vb >> 6) * 128;
        float acc[8];
        #pragma unroll
        for (int e = 0; e < 8; ++e) acc[e] = 0.f;

        for (int dt = 0; dt < 4; ++dt) {
            if (dt) __syncthreads();
            #pragma unroll
            for (int r = 0; r < 8; ++r) {
                int fi = r * 256 + tid;       // = token*8 + dj
                int token = fi >> 3, dj = fi & 7;
                const float4 v = *(const float4*)
                    &X[(size_t)(bt0 + token) * D_ + d0 + dt * 32 + dj * 4];
                *(float4*)&lds[token * 36 + dj * 4] = v;
            }
            __syncthreads();
            #pragma unroll
            for (int dj = 0; dj < 8; ++dj) {
                const float4 x4 = *(const float4*)&lds[tid * 36 + dj * 4];
                const int db = d0 + dt * 32 + dj * 4;      // block-uniform
                const float xv[4] = {x4.x, x4.y, x4.z, x4.w};
                #pragma unroll
                for (int rr = 0; rr < 4; ++rr) {
                    const float4 wlo = *(const float4*)&Wg[(size_t)(db + rr) * 8];
                    const float4 whi = *(const float4*)&Wg[(size_t)(db + rr) * 8 + 4];
                    acc[0] += xv[rr]*wlo.x; acc[1] += xv[rr]*wlo.y;
                    acc[2] += xv[rr]*wlo.z; acc[3] += xv[rr]*wlo.w;
                    acc[4] += xv[rr]*whi.x; acc[5] += xv[rr]*whi.y;
                    acc[6] += xv[rr]*whi.z; acc[7] += xv[rr]*whi.w;
                }
            }
        }
        float* pp = &outbuf[LPART_F + (size_t)(vb >> 6) * BT_ * E_
                            + (size_t)(bt0 + tid) * E_];
        *(float4*)&pp[0] = make_float4(acc[0], acc[1], acc[2], acc[3]);
        *(float4*)&pp[4] = make_float4(acc[4], acc[5], acc[6], acc[7]);
    }
    gsync(bar, NBLK);

    // ----- P1: merge logits + exp (UNNORMALIZED) + slot partials (X pass 2) -----
    if (vb < 256) {
        const int ts = vb & 31, b = vb >> 5;
        const int t0 = ts * 64;
        float* wlds = lds;                       // 512 floats

        #pragma unroll
        for (int r = 0; r < 2; ++r) {
            int idx = r * 256 + tid;             // = t*8 + e
            int t = idx >> 3, e = idx & 7;
            float a = bg[e];
            #pragma unroll
            for (int dc = 0; dc < 8; ++dc)
                a += outbuf[LPART_F + (size_t)dc * BT_ * E_
                            + ((size_t)b * T_ + t0 + t) * E_ + e];
            logits[((size_t)b * T_ + t0 + t) * E_ + e] = a;
            wlds[idx] = expf(a);                 // unnormalized dispatch weight
        }
        __syncthreads();
        if (tid < 8) {                           // per-block sumexp partial
            float s = 0.f;
            for (int t = 0; t < 64; ++t) s += wlds[t * 8 + tid];
            sexp[(b * 32 + ts) * 8 + tid] = s;
        }

        float4 acc[8];
        #pragma unroll
        for (int e = 0; e < 8; ++e) acc[e] = make_float4(0.f, 0.f, 0.f, 0.f);

        const float* xb = &X[((size_t)b * T_ + t0) * D_ + tid * 4];
        #pragma unroll 8
        for (int t = 0; t < 64; ++t) {
            const float4 x4 = *(const float4*)&xb[(size_t)t * D_];
            const float4 wA = *(const float4*)&wlds[t * 8];       // broadcast
            const float4 wB = *(const float4*)&wlds[t * 8 + 4];   // broadcast
            const float w[8] = {wA.x, wA.y, wA.z, wA.w, wB.x, wB.y, wB.z, wB.w};
            #pragma unroll
            for (int e = 0; e < 8; ++e) {
                acc[e].x += x4.x * w[e];
                acc[e].y += x4.y * w[e];
                acc[e].z += x4.z * w[e];
                acc[e].w += x4.w * w[e];
            }
        }
        #pragma unroll
        for (int e = 0; e < 8; ++e)
            *(float4*)&outbuf[SPART_F + (size_t)ts * (N_ * D_)
                              + (size_t)(b * E_ + e) * D_ + tid * 4] = acc[e];
    }
    gsync(bar, 2 * NBLK);

    // ----- P2: reduce 32 slot partials, normalize by sumexp -----
    {
        const int gid = vb * 256 + tid;
        if (gid < 65536) {
            const int row = gid >> 10;           // b*8+e
            const int b = row >> 3, e = row & 7;
            float se = 0.f;
            #pragma unroll
            for (int t = 0; t < 32; ++t) se += sexp[(b * 32 + t) * 8 + e];
            float s = 0.f;
            #pragma unroll
            for (int p = 0; p < 32; ++p)
                s += outbuf[SPART_F + (size_t)p * (N_ * D_) + gid];
            slots[gid] = s / se;
        }
    }
    gsync(bar, 3 * NBLK);

    // ----- P3: GEMM1 partials (64 f-chunks x 8 k-chunks = 512 tiles) -----
    gemm_phase<1024, 4096>(slots, W1, &outbuf[G1PART_F], lds, vb >> 3, vb & 7);
    gsync(bar, 4 * NBLK);

    // ----- P4: reduce 8 + bias + SiLU -> h[64][4096] -----
    {
        #pragma unroll
        for (int s = 0; s < 2; ++s) {
            const int i = s * 131072 + vb * 256 + tid;
            float v = b1[i & (FF_ - 1)];
            #pragma unroll
            for (int p = 0; p < 8; ++p)
                v += outbuf[G1PART_F + (size_t)p * (N_ * FF_) + i];
            h[i] = v / (1.f + expf(-v));
        }
    }
    gsync(bar, 5 * NBLK);

    // ----- P5: GEMM2 partials (16 f-chunks x 32 k-chunks = 512 tiles) -----
    gemm_phase<4096, 1024>(h, W2, &outbuf[G2PART_F], lds, vb >> 5, vb & 31);
    gsync(bar, 6 * NBLK);

    // ----- P6: reduce 32 + bias -> y[64][1024] -----
    {
        const int gid = vb * 256 + tid;
        if (gid < 65536) {
            float v = b2[gid & (D_ - 1)];
            #pragma unroll
            for (int p = 0; p < 32; ++p)
                v += outbuf[G2PART_F + (size_t)p * (N_ * D_) + gid];
            y[gid] = v;
        }
    }
    gsync(bar, 7 * NBLK);

    // ----- P7: combine -> out (overwrites all partial regions) -----
    {
        float* wlds = lds;
        #pragma unroll
        for (int s = 0; s < 2; ++s) {
            const int cb = vb * 2 + s;           // 1024 logical tiles
            const int dc = cb & 3, tc = (cb >> 2) & 31, b = cb >> 7;
            const int t0 = tc * 64;

            __syncthreads();                     // protect wlds reuse
            if (tid < 64) {
                const float* lp = &logits[((size_t)b * T_ + t0 + tid) * E_];
                float ex[8]; float sm = 0.f;
                #pragma unroll
                for (int i = 0; i < 8; ++i) { ex[i] = expf(lp[i]); sm += ex[i]; }
                const float invs = 1.f / sm;
                #pragma unroll
                for (int i = 0; i < 8; ++i) wlds[tid * 8 + i] = ex[i] * invs;
            }
            __syncthreads();

            const int d = dc * 256 + tid;
            float yv[8];
            #pragma unroll
            for (int e = 0; e < 8; ++e) yv[e] = y[(size_t)(b * E_ + e) * D_ + d];

            for (int t = 0; t < 64; ++t) {
                const float4 wA = *(const float4*)&wlds[t * 8];
                const float4 wB = *(const float4*)&wlds[t * 8 + 4];
                const float acc = wA.x*yv[0] + wA.y*yv[1] + wA.z*yv[2] + wA.w*yv[3]
                                + wB.x*yv[4] + wB.y*yv[5] + wB.z*yv[6] + wB.w*yv[7];
                outbuf[((size_t)b * T_ + t0 + t) * D_ + d] = acc;
            }
        }
    }
}

// ---------------------------------------------------------------------------
extern "C" void kernel_launch(void* const* d_in, const int* in_sizes, int n_in,
                              void* d_out, int out_size, void* d_ws, size_t ws_size,
                              hipStream_t stream)
{
    const float* X  = (const float*)d_in[0];
    const float* Wg = (const float*)d_in[1];
    const float* bg = (const float*)d_in[2];
    const float* W1 = (const float*)d_in[3];
    const float* b1 = (const float*)d_in[4];
    const float* W2 = (const float*)d_in[5];
    const float* b2 = (const float*)d_in[6];
    float* out = (float*)d_out;

    // ws layout (fp32), ~2.1 MB
    float* wsf    = (float*)d_ws;
    int*   bar    = (int*)d_ws;                 // barrier counter (cacheline 0)
    float* logits = wsf + 64;                   // 131072
    float* sexp   = logits + BT_ * E_;          // 2048 (32 slices x 8 b x 8 e)
    float* slots  = sexp + 2048;                // 65536
    float* h      = slots + N_ * D_;            // 262144
    float* y      = h + N_ * FF_;               // 65536

    hipMemsetAsync(d_ws, 0, 256, stream);
    hipLaunchKernelGGL(k_mega, dim3(NBLK), dim3(256), 0, stream,
                       X, Wg, bg, W1, b1, W2, b2, out,
                       logits, sexp, slots, h, y, bar);
}

// Round 6
// 285.212 us; speedup vs baseline: 2.1615x; 2.0133x over previous
//
#include <hip/hip_runtime.h>
#include <math.h>

#define B_  8
#define T_  2048
#define D_  1024
#define E_  8
#define FF_ 4096
#define N_  64            // B*E rows through the FFN
#define BT_ (B_*T_)

// ---- d_out scratch regions (float offsets), all dead before k_combine ----
// LPART  [0 .. 1048576)         : logit partials [8][BT][8]   4 MB (dead after merge)
// HACC   [0 .. 262144)          : gemm1 atomic accum          1 MB (reuses dead LPART)
// H      [262144 .. 524288)     : silu output                 1 MB (reuses dead LPART)
// SPART  [1048576 .. 5242880)   : slot partials [64][64][1024] 16 MB
#define LPART_F  0u
#define HACC_F   0u
#define H_F      262144u
#define SPART_F  1048576u

// ---------------------------------------------------------------------------
// K1a: partial logits over a 128-d chunk. grid (BT/256, 8), 256 threads.
// Thread owns ONE token, all 8 experts. X staged in LDS (coalesced);
// Wg read with block-uniform addresses -> scalar s_load path.
// ---------------------------------------------------------------------------
__global__ __launch_bounds__(256) void k_logits_part(
    const float* __restrict__ X, const float* __restrict__ Wg,
    float* __restrict__ part)
{
    __shared__ float xt[256 * 36];       // 256 tokens x 32 d (pad 36), 36 KB

    const int tid = threadIdx.x;
    const int bt0 = blockIdx.x * 256;
    const int d0  = blockIdx.y * 128;

    float acc[8];
    #pragma unroll
    for (int e = 0; e < 8; ++e) acc[e] = 0.f;

    for (int dt = 0; dt < 4; ++dt) {
        if (dt) __syncthreads();          // WAR: previous compute vs restage
        #pragma unroll
        for (int r = 0; r < 8; ++r) {
            int fi = r * 256 + tid;       // float4 index = token*8 + dj
            int token = fi >> 3, dj = fi & 7;
            const float4 v = *(const float4*)
                &X[(size_t)(bt0 + token) * D_ + d0 + dt * 32 + dj * 4];
            *(float4*)&xt[token * 36 + dj * 4] = v;
        }
        __syncthreads();
        #pragma unroll
        for (int dj = 0; dj < 8; ++dj) {
            const float4 x4 = *(const float4*)&xt[tid * 36 + dj * 4];
            const int db = d0 + dt * 32 + dj * 4;      // block-uniform
            const float xv[4] = {x4.x, x4.y, x4.z, x4.w};
            #pragma unroll
            for (int r = 0; r < 4; ++r) {
                const float4 wlo = *(const float4*)&Wg[(size_t)(db + r) * 8];
                const float4 whi = *(const float4*)&Wg[(size_t)(db + r) * 8 + 4];
                acc[0] += xv[r] * wlo.x; acc[1] += xv[r] * wlo.y;
                acc[2] += xv[r] * wlo.z; acc[3] += xv[r] * wlo.w;
                acc[4] += xv[r] * whi.x; acc[5] += xv[r] * whi.y;
                acc[6] += xv[r] * whi.z; acc[7] += xv[r] * whi.w;
            }
        }
    }

    float* pp = &part[LPART_F + (size_t)blockIdx.y * BT_ * E_
                      + (size_t)(bt0 + tid) * E_];
    *(float4*)&pp[0] = make_float4(acc[0], acc[1], acc[2], acc[3]);
    *(float4*)&pp[4] = make_float4(acc[4], acc[5], acc[6], acc[7]);
}

// ---------------------------------------------------------------------------
// K1b: merge 8 d-chunk partials + bg -> logits; per-block per-e sum of exp
// written to sexp_part[blk][8] (no atomics). grid (BT/256) = 64.
// ---------------------------------------------------------------------------
__global__ __launch_bounds__(256) void k_logits_merge(
    const float* __restrict__ part, const float* __restrict__ bg,
    float* __restrict__ logits, float* __restrict__ sexp_part)
{
    __shared__ float red[8 * 256];
    const int tid = threadIdx.x;
    const int token = blockIdx.x * 256 + tid;

    float a[8];
    #pragma unroll
    for (int e = 0; e < 8; ++e) a[e] = 0.f;
    #pragma unroll
    for (int p = 0; p < 8; ++p) {
        const float* pp = &part[LPART_F + (size_t)p * BT_ * E_
                                + (size_t)token * E_];
        const float4 v0 = *(const float4*)&pp[0];
        const float4 v1 = *(const float4*)&pp[4];
        a[0] += v0.x; a[1] += v0.y; a[2] += v0.z; a[3] += v0.w;
        a[4] += v1.x; a[5] += v1.y; a[6] += v1.z; a[7] += v1.w;
    }
    #pragma unroll
    for (int e = 0; e < 8; ++e) a[e] += bg[e];

    float* lp = &logits[(size_t)token * E_];
    *(float4*)&lp[0] = make_float4(a[0], a[1], a[2], a[3]);
    *(float4*)&lp[4] = make_float4(a[4], a[5], a[6], a[7]);

    #pragma unroll
    for (int e = 0; e < 8; ++e) red[e * 256 + tid] = expf(a[e]);
    __syncthreads();
    for (int s = 128; s >= 1; s >>= 1) {
        if (tid < s) {
            #pragma unroll
            for (int e = 0; e < 8; ++e)
                red[e * 256 + tid] += red[e * 256 + tid + s];
        }
        __syncthreads();
    }
    if (tid < 8) sexp_part[blockIdx.x * 8 + tid] = red[tid * 256];
}

// ---------------------------------------------------------------------------
// K2: slots partials. grid (64 slices of 32 tokens, 8 b) = 512 blocks.
// Reduces the 8 sexp_part blocks of this batch -> inv[8], then accumulates
// dispatch_w * X. Thread owns one d-float4.
// ---------------------------------------------------------------------------
__global__ __launch_bounds__(256) void k_slots_part(
    const float* __restrict__ X, const float* __restrict__ logits,
    const float* __restrict__ sexp_part, float* __restrict__ part)
{
    __shared__ float wlds[32 * 8];
    __shared__ float red[64];
    __shared__ float inv[8];

    const int tid = threadIdx.x;
    const int ts = blockIdx.x, b = blockIdx.y;
    const int t0 = ts * 32;

    if (tid < 64) red[tid] = sexp_part[b * 64 + tid];   // [blk-in-b][e]
    __syncthreads();
    if (tid < 8) {
        float s = 0.f;
        #pragma unroll
        for (int i = 0; i < 8; ++i) s += red[i * 8 + tid];
        inv[tid] = 1.f / s;
    }
    __syncthreads();
    {
        int t = tid >> 3, e = tid & 7;    // 256 threads = 32 tokens x 8 e
        wlds[tid] = expf(logits[((size_t)b * T_ + t0 + t) * E_ + e]) * inv[e];
    }
    __syncthreads();

    float4 acc[8];
    #pragma unroll
    for (int e = 0; e < 8; ++e) acc[e] = make_float4(0.f, 0.f, 0.f, 0.f);

    const float* xb = &X[((size_t)b * T_ + t0) * D_ + tid * 4];
    #pragma unroll 8
    for (int t = 0; t < 32; ++t) {
        const float4 x4 = *(const float4*)&xb[(size_t)t * D_];
        const float4 wA = *(const float4*)&wlds[t * 8];       // broadcast
        const float4 wB = *(const float4*)&wlds[t * 8 + 4];   // broadcast
        const float w[8] = {wA.x, wA.y, wA.z, wA.w, wB.x, wB.y, wB.z, wB.w};
        #pragma unroll
        for (int e = 0; e < 8; ++e) {
            acc[e].x += x4.x * w[e];
            acc[e].y += x4.y * w[e];
            acc[e].z += x4.z * w[e];
            acc[e].w += x4.w * w[e];
        }
    }
    #pragma unroll
    for (int e = 0; e < 8; ++e) {
        *(float4*)&part[SPART_F + (size_t)ts * (N_ * D_)
                        + (size_t)(b * E_ + e) * D_ + tid * 4] = acc[e];
    }
}

// K3: reduce 64 slot partials -> slots[64][1024]. grid 256.
__global__ __launch_bounds__(256) void k_reduce_slots(
    const float* __restrict__ part, float* __restrict__ slots)
{
    const int i = blockIdx.x * 256 + threadIdx.x;     // 65536
    float s = 0.f;
    #pragma unroll
    for (int p = 0; p < 64; ++p)
        s += part[SPART_F + (size_t)p * (N_ * D_) + i];
    slots[i] = s;
}

// ---------------------------------------------------------------------------
// K4/K6: k-split GEMM, KT=128, atomic accumulation (no partials/reduce).
// Tile 64 rows x 64 cols, 256 threads: thread = (rg=tid>>4: 4 rows,
// cg=tid&15: 4 cols); acc = 4 x float4 = 16 VGPR. As padded to 132/row
// (132%32=4 -> 4-row broadcast reads conflict-free). grid (F/64, K/128).
// Epilogue: 16 unsafeAtomicAdd (native global_atomic_add_f32).
// ---------------------------------------------------------------------------
template<int K, int F>
__global__ __launch_bounds__(256) void k_gemm_atomic(
    const float* __restrict__ A, const float* __restrict__ W,
    float* __restrict__ outp)
{
    __shared__ float As[64 * 132];                // 33.8 KB

    const int tid = threadIdx.x;
    const int rg = tid >> 4, cg = tid & 15;
    const int f0 = blockIdx.x * 64 + cg * 4;
    const int k0 = blockIdx.y * 128;

    #pragma unroll
    for (int i = 0; i < 8; ++i) {                 // 2048 float4, coalesced
        int idx = i * 256 + tid;
        int row = idx >> 5, kq = idx & 31;
        *(float4*)&As[row * 132 + kq * 4] =
            *(const float4*)&A[(size_t)row * K + k0 + kq * 4];
    }
    __syncthreads();

    float4 acc[4];
    #pragma unroll
    for (int r = 0; r < 4; ++r) acc[r] = make_float4(0.f, 0.f, 0.f, 0.f);

    #pragma unroll 2
    for (int kq = 0; kq < 32; ++kq) {
        const float* wr = &W[(size_t)(k0 + kq * 4) * F + f0];
        const float4 w0 = *(const float4*)&wr[0];
        const float4 w1 = *(const float4*)&wr[(size_t)F];
        const float4 w2 = *(const float4*)&wr[2 * (size_t)F];
        const float4 w3 = *(const float4*)&wr[3 * (size_t)F];
        #pragma unroll
        for (int r = 0; r < 4; ++r) {
            const float4 a = *(const float4*)&As[(rg * 4 + r) * 132 + kq * 4];
            acc[r].x += a.x*w0.x + a.y*w1.x + a.z*w2.x + a.w*w3.x;
            acc[r].y += a.x*w0.y + a.y*w1.y + a.z*w2.y + a.w*w3.y;
            acc[r].z += a.x*w0.z + a.y*w1.z + a.z*w2.z + a.w*w3.z;
            acc[r].w += a.x*w0.w + a.y*w1.w + a.z*w2.w + a.w*w3.w;
        }
    }

    #pragma unroll
    for (int r = 0; r < 4; ++r) {
        float* op = &outp[(size_t)(rg * 4 + r) * F + f0];
        unsafeAtomicAdd(&op[0], acc[r].x);
        unsafeAtomicAdd(&op[1], acc[r].y);
        unsafeAtomicAdd(&op[2], acc[r].z);
        unsafeAtomicAdd(&op[3], acc[r].w);
    }
}

// K5: h = silu(hacc + b1), float4 per thread. grid 256.
__global__ __launch_bounds__(256) void k_silu(
    const float* __restrict__ hacc, const float* __restrict__ b1,
    float* __restrict__ h)
{
    const int i4 = blockIdx.x * 256 + threadIdx.x;    // 65536 float4s
    const float4 v = *(const float4*)&hacc[(size_t)i4 * 4];
    const float4 bb = *(const float4*)&b1[(i4 * 4) & (FF_ - 1)];
    float4 r;
    r.x = v.x + bb.x; r.y = v.y + bb.y; r.z = v.z + bb.z; r.w = v.w + bb.w;
    r.x = r.x / (1.f + expf(-r.x));
    r.y = r.y / (1.f + expf(-r.y));
    r.z = r.z / (1.f + expf(-r.z));
    r.w = r.w / (1.f + expf(-r.w));
    *(float4*)&h[(size_t)i4 * 4] = r;
}

// ---------------------------------------------------------------------------
// K8: out[b][t][d] = sum_e softmax_e(logits[b,t,:])[e] * (yacc[b*8+e][d]+b2[d])
// ---------------------------------------------------------------------------
__global__ __launch_bounds__(256) void k_combine(
    const float* __restrict__ logits, const float* __restrict__ yacc,
    const float* __restrict__ b2, float* __restrict__ out)
{
    __shared__ float wlds[64 * 8];
    const int tid = threadIdx.x;
    const int dc = blockIdx.x, tc = blockIdx.y, b = blockIdx.z;
    const int t0 = tc * 64;

    if (tid < 64) {
        const float* lp = &logits[((size_t)b * T_ + t0 + tid) * E_];
        float ex[8]; float s = 0.f;
        #pragma unroll
        for (int i = 0; i < 8; ++i) { ex[i] = expf(lp[i]); s += ex[i]; }
        const float invs = 1.f / s;
        #pragma unroll
        for (int i = 0; i < 8; ++i) wlds[tid * 8 + i] = ex[i] * invs;
    }
    __syncthreads();

    const int d = dc * 256 + tid;
    const float bv = b2[d];
    float yv[8];
    #pragma unroll
    for (int e = 0; e < 8; ++e)
        yv[e] = yacc[(size_t)(b * E_ + e) * D_ + d] + bv;

    for (int t = 0; t < 64; ++t) {
        const float4 wA = *(const float4*)&wlds[t * 8];
        const float4 wB = *(const float4*)&wlds[t * 8 + 4];
        const float acc = wA.x*yv[0] + wA.y*yv[1] + wA.z*yv[2] + wA.w*yv[3]
                        + wB.x*yv[4] + wB.y*yv[5] + wB.z*yv[6] + wB.w*yv[7];
        out[((size_t)b * T_ + t0 + t) * D_ + d] = acc;
    }
}

// ---------------------------------------------------------------------------
extern "C" void kernel_launch(void* const* d_in, const int* in_sizes, int n_in,
                              void* d_out, int out_size, void* d_ws, size_t ws_size,
                              hipStream_t stream)
{
    const float* X  = (const float*)d_in[0];
    const float* Wg = (const float*)d_in[1];
    const float* bg = (const float*)d_in[2];
    const float* W1 = (const float*)d_in[3];
    const float* b1 = (const float*)d_in[4];
    const float* W2 = (const float*)d_in[5];
    const float* b2 = (const float*)d_in[6];
    float* out = (float*)d_out;

    // ws (fp32), ~1.1 MB: logits | sexp_part | slots | yacc
    float* wsf       = (float*)d_ws;
    float* logits    = wsf;                        // 131072
    float* sexp_part = logits + BT_ * E_;          // 512 (64 blocks x 8 e)
    float* slots     = sexp_part + 512;            // 65536
    float* yacc      = slots + N_ * D_;            // 65536

    // d_out scratch: LPART (dead after merge) -> reused as HACC + H.
    float* hacc = out + HACC_F;                    // 262144 floats
    float* h    = out + H_F;                       // 262144 floats

    hipLaunchKernelGGL(k_logits_part,  dim3(BT_ / 256, 8), dim3(256), 0, stream,
                       X, Wg, out);
    hipLaunchKernelGGL(k_logits_merge, dim3(BT_ / 256),    dim3(256), 0, stream,
                       out, bg, logits, sexp_part);
    hipLaunchKernelGGL(k_slots_part,   dim3(64, 8),        dim3(256), 0, stream,
                       X, logits, sexp_part, out);
    hipLaunchKernelGGL(k_reduce_slots, dim3(256),          dim3(256), 0, stream,
                       out, slots);
    // zero atomic accumulators (LPART now dead; yacc in ws untouched so far)
    hipMemsetAsync(hacc, 0, (size_t)N_ * FF_ * sizeof(float), stream);
    hipMemsetAsync(yacc, 0, (size_t)N_ * D_ * sizeof(float), stream);
    hipLaunchKernelGGL((k_gemm_atomic<1024, 4096>), dim3(FF_ / 64, 1024 / 128),
                       dim3(256), 0, stream, slots, W1, hacc);
    hipLaunchKernelGGL(k_silu,         dim3(N_ * FF_ / 1024), dim3(256), 0, stream,
                       hacc, b1, h);
    hipLaunchKernelGGL((k_gemm_atomic<4096, 1024>), dim3(D_ / 64, FF_ / 128),
                       dim3(256), 0, stream, h, W2, yacc);
    hipLaunchKernelGGL(k_combine,      dim3(4, 32, 8), dim3(256), 0, stream,
                       logits, yacc, b2, out);
}

// Round 7
// 284.266 us; speedup vs baseline: 2.1686x; 1.0033x over previous
//
#include <hip/hip_runtime.h>
#include <math.h>

#define B_  8
#define T_  2048
#define D_  1024
#define E_  8
#define FF_ 4096
#define N_  64            // B*E rows through the FFN
#define BT_ (B_*T_)

// ---- d_out scratch regions (float offsets), all dead before k_combine ----
#define LPART_F  0u           // [8][BT][8]       4 MB (dead after merge)
#define SPART_F  1048576u     // [64][64][1024]  16 MB (slot partials)
#define G1PART_F 5242880u     // [2][64][4096]    2 MB
#define G2PART_F 5767168u     // [8][64][1024]    2 MB

// ---------------------------------------------------------------------------
// K1a: partial logits over a 128-d chunk. grid (BT/256, 8), 256 threads.
// Thread owns ONE token, all 8 experts. X staged in LDS (coalesced);
// Wg read with block-uniform addresses -> scalar s_load path.
// ---------------------------------------------------------------------------
__global__ __launch_bounds__(256) void k_logits_part(
    const float* __restrict__ X, const float* __restrict__ Wg,
    float* __restrict__ part)
{
    __shared__ float xt[256 * 36];       // 256 tokens x 32 d (pad 36), 36 KB

    const int tid = threadIdx.x;
    const int bt0 = blockIdx.x * 256;
    const int d0  = blockIdx.y * 128;

    float acc[8];
    #pragma unroll
    for (int e = 0; e < 8; ++e) acc[e] = 0.f;

    for (int dt = 0; dt < 4; ++dt) {
        if (dt) __syncthreads();          // WAR: previous compute vs restage
        #pragma unroll
        for (int r = 0; r < 8; ++r) {
            int fi = r * 256 + tid;       // float4 index = token*8 + dj
            int token = fi >> 3, dj = fi & 7;
            const float4 v = *(const float4*)
                &X[(size_t)(bt0 + token) * D_ + d0 + dt * 32 + dj * 4];
            *(float4*)&xt[token * 36 + dj * 4] = v;
        }
        __syncthreads();
        #pragma unroll
        for (int dj = 0; dj < 8; ++dj) {
            const float4 x4 = *(const float4*)&xt[tid * 36 + dj * 4];
            const int db = d0 + dt * 32 + dj * 4;      // block-uniform
            const float xv[4] = {x4.x, x4.y, x4.z, x4.w};
            #pragma unroll
            for (int r = 0; r < 4; ++r) {
                const float4 wlo = *(const float4*)&Wg[(size_t)(db + r) * 8];
                const float4 whi = *(const float4*)&Wg[(size_t)(db + r) * 8 + 4];
                acc[0] += xv[r] * wlo.x; acc[1] += xv[r] * wlo.y;
                acc[2] += xv[r] * wlo.z; acc[3] += xv[r] * wlo.w;
                acc[4] += xv[r] * whi.x; acc[5] += xv[r] * whi.y;
                acc[6] += xv[r] * whi.z; acc[7] += xv[r] * whi.w;
            }
        }
    }

    float* pp = &part[LPART_F + (size_t)blockIdx.y * BT_ * E_
                      + (size_t)(bt0 + tid) * E_];
    *(float4*)&pp[0] = make_float4(acc[0], acc[1], acc[2], acc[3]);
    *(float4*)&pp[4] = make_float4(acc[4], acc[5], acc[6], acc[7]);
}

// ---------------------------------------------------------------------------
// K1b: merge 8 d-chunk partials + bg -> logits; per-block per-e sum of exp
// written to sexp_part[blk][8] (no atomics). grid (BT/256) = 64.
// ---------------------------------------------------------------------------
__global__ __launch_bounds__(256) void k_logits_merge(
    const float* __restrict__ part, const float* __restrict__ bg,
    float* __restrict__ logits, float* __restrict__ sexp_part)
{
    __shared__ float red[8 * 256];
    const int tid = threadIdx.x;
    const int token = blockIdx.x * 256 + tid;

    float a[8];
    #pragma unroll
    for (int e = 0; e < 8; ++e) a[e] = 0.f;
    #pragma unroll
    for (int p = 0; p < 8; ++p) {
        const float* pp = &part[LPART_F + (size_t)p * BT_ * E_
                                + (size_t)token * E_];
        const float4 v0 = *(const float4*)&pp[0];
        const float4 v1 = *(const float4*)&pp[4];
        a[0] += v0.x; a[1] += v0.y; a[2] += v0.z; a[3] += v0.w;
        a[4] += v1.x; a[5] += v1.y; a[6] += v1.z; a[7] += v1.w;
    }
    #pragma unroll
    for (int e = 0; e < 8; ++e) a[e] += bg[e];

    float* lp = &logits[(size_t)token * E_];
    *(float4*)&lp[0] = make_float4(a[0], a[1], a[2], a[3]);
    *(float4*)&lp[4] = make_float4(a[4], a[5], a[6], a[7]);

    #pragma unroll
    for (int e = 0; e < 8; ++e) red[e * 256 + tid] = expf(a[e]);
    __syncthreads();
    for (int s = 128; s >= 1; s >>= 1) {
        if (tid < s) {
            #pragma unroll
            for (int e = 0; e < 8; ++e)
                red[e * 256 + tid] += red[e * 256 + tid + s];
        }
        __syncthreads();
    }
    if (tid < 8) sexp_part[blockIdx.x * 8 + tid] = red[tid * 256];
}

// ---------------------------------------------------------------------------
// K2: slots partials. grid (64 slices of 32 tokens, 8 b) = 512 blocks.
// ---------------------------------------------------------------------------
__global__ __launch_bounds__(256) void k_slots_part(
    const float* __restrict__ X, const float* __restrict__ logits,
    const float* __restrict__ sexp_part, float* __restrict__ part)
{
    __shared__ float wlds[32 * 8];
    __shared__ float red[64];
    __shared__ float inv[8];

    const int tid = threadIdx.x;
    const int ts = blockIdx.x, b = blockIdx.y;
    const int t0 = ts * 32;

    if (tid < 64) red[tid] = sexp_part[b * 64 + tid];   // [blk-in-b][e]
    __syncthreads();
    if (tid < 8) {
        float s = 0.f;
        #pragma unroll
        for (int i = 0; i < 8; ++i) s += red[i * 8 + tid];
        inv[tid] = 1.f / s;
    }
    __syncthreads();
    {
        int t = tid >> 3, e = tid & 7;    // 256 threads = 32 tokens x 8 e
        wlds[tid] = expf(logits[((size_t)b * T_ + t0 + t) * E_ + e]) * inv[e];
    }
    __syncthreads();

    float4 acc[8];
    #pragma unroll
    for (int e = 0; e < 8; ++e) acc[e] = make_float4(0.f, 0.f, 0.f, 0.f);

    const float* xb = &X[((size_t)b * T_ + t0) * D_ + tid * 4];
    #pragma unroll 8
    for (int t = 0; t < 32; ++t) {
        const float4 x4 = *(const float4*)&xb[(size_t)t * D_];
        const float4 wA = *(const float4*)&wlds[t * 8];       // broadcast
        const float4 wB = *(const float4*)&wlds[t * 8 + 4];   // broadcast
        const float w[8] = {wA.x, wA.y, wA.z, wA.w, wB.x, wB.y, wB.z, wB.w};
        #pragma unroll
        for (int e = 0; e < 8; ++e) {
            acc[e].x += x4.x * w[e];
            acc[e].y += x4.y * w[e];
            acc[e].z += x4.z * w[e];
            acc[e].w += x4.w * w[e];
        }
    }
    #pragma unroll
    for (int e = 0; e < 8; ++e) {
        *(float4*)&part[SPART_F + (size_t)ts * (N_ * D_)
                        + (size_t)(b * E_ + e) * D_ + tid * 4] = acc[e];
    }
}

// K3: reduce 64 slot partials -> slots[64][1024]. grid 256.
__global__ __launch_bounds__(256) void k_reduce_slots(
    const float* __restrict__ part, float* __restrict__ slots)
{
    const int i = blockIdx.x * 256 + threadIdx.x;     // 65536
    float s = 0.f;
    #pragma unroll
    for (int p = 0; p < 64; ++p)
        s += part[SPART_F + (size_t)p * (N_ * D_) + i];
    slots[i] = s;
}

// ---------------------------------------------------------------------------
// K4/K6: skinny split-K GEMM, NO atomics. Tile 64 rows x 16 cols, K_block =
// K/KSPLIT = 512 in 4 LDS-staged chunks of 128. Thread = 1 row x 4 cols
// (row = tid>>2, cg = tid&3): acc = one float4. A-tile padded to 132/row:
// inner read = 16 distinct rows, 2-way bank alias (free), 4-lane broadcast.
// W reads: 4 distinct float4 per load inst -> one 64B request, L1-absorbed
// redundancy. grid (F/16, KSPLIT) = 512 blocks -> 2 blocks/CU.
// part[kc][row][f] written direct (no contention).
// ---------------------------------------------------------------------------
template<int K, int F, int KSPLIT>
__global__ __launch_bounds__(256, 2) void k_ffn(
    const float* __restrict__ A, const float* __restrict__ W,
    float* __restrict__ part)
{
    __shared__ float As[64 * 132];                // 33 KB

    const int tid = threadIdx.x;
    const int row = tid >> 2;                     // 0..63
    const int cg  = tid & 3;                      // 0..3
    const int f0  = blockIdx.x * 16 + cg * 4;
    const int k0  = blockIdx.y * (K / KSPLIT);

    float4 acc = make_float4(0.f, 0.f, 0.f, 0.f);

    for (int c = 0; c < (K / KSPLIT) / 128; ++c) {
        const int kb = k0 + c * 128;
        if (c) __syncthreads();
        #pragma unroll
        for (int i = 0; i < 8; ++i) {             // 2048 float4, coalesced
            int idx = i * 256 + tid;
            int r = idx >> 5, kq = idx & 31;
            *(float4*)&As[r * 132 + kq * 4] =
                *(const float4*)&A[(size_t)r * K + kb + kq * 4];
        }
        __syncthreads();
        #pragma unroll 4
        for (int kq = 0; kq < 32; ++kq) {
            const float* wr = &W[(size_t)(kb + kq * 4) * F + f0];
            const float4 w0 = *(const float4*)&wr[0];
            const float4 w1 = *(const float4*)&wr[(size_t)F];
            const float4 w2 = *(const float4*)&wr[2 * (size_t)F];
            const float4 w3 = *(const float4*)&wr[3 * (size_t)F];
            const float4 a = *(const float4*)&As[row * 132 + kq * 4];
            acc.x += a.x*w0.x + a.y*w1.x + a.z*w2.x + a.w*w3.x;
            acc.y += a.x*w0.y + a.y*w1.y + a.z*w2.y + a.w*w3.y;
            acc.z += a.x*w0.z + a.y*w1.z + a.z*w2.z + a.w*w3.z;
            acc.w += a.x*w0.w + a.y*w1.w + a.z*w2.w + a.w*w3.w;
        }
    }

    *(float4*)&part[(size_t)blockIdx.y * (N_ * F) + (size_t)row * F + f0] = acc;
}

// K5: h = silu(sum of 2 gemm1 partials + b1). grid 256, float4/thread.
__global__ __launch_bounds__(256) void k_reduce_silu(
    const float* __restrict__ part, const float* __restrict__ b1,
    float* __restrict__ h)
{
    const int i4 = blockIdx.x * 256 + threadIdx.x;    // 65536 float4s
    const float4 v0 = *(const float4*)&part[G1PART_F + (size_t)i4 * 4];
    const float4 v1 = *(const float4*)&part[G1PART_F + (size_t)(N_ * FF_) + (size_t)i4 * 4];
    const float4 bb = *(const float4*)&b1[(i4 & (FF_ / 4 - 1)) * 4];
    float4 r;
    r.x = v0.x + v1.x + bb.x; r.y = v0.y + v1.y + bb.y;
    r.z = v0.z + v1.z + bb.z; r.w = v0.w + v1.w + bb.w;
    r.x = r.x / (1.f + expf(-r.x));
    r.y = r.y / (1.f + expf(-r.y));
    r.z = r.z / (1.f + expf(-r.z));
    r.w = r.w / (1.f + expf(-r.w));
    *(float4*)&h[(size_t)i4 * 4] = r;
}

// K7: y = sum of 8 gemm2 partials + b2. grid 64, float4/thread.
__global__ __launch_bounds__(256) void k_reduce_bias(
    const float* __restrict__ part, const float* __restrict__ b2,
    float* __restrict__ y)
{
    const int i4 = blockIdx.x * 256 + threadIdx.x;    // 16384 float4s
    const float4 bb = *(const float4*)&b2[(i4 & (D_ / 4 - 1)) * 4];
    float4 r = bb;
    #pragma unroll
    for (int p = 0; p < 8; ++p) {
        const float4 v = *(const float4*)
            &part[G2PART_F + (size_t)p * (N_ * D_) + (size_t)i4 * 4];
        r.x += v.x; r.y += v.y; r.z += v.z; r.w += v.w;
    }
    *(float4*)&y[(size_t)i4 * 4] = r;
}

// ---------------------------------------------------------------------------
// K8: out[b][t][d] = sum_e softmax_e(logits[b,t,:])[e] * y[b*8+e][d]
// ---------------------------------------------------------------------------
__global__ __launch_bounds__(256) void k_combine(
    const float* __restrict__ logits, const float* __restrict__ y,
    float* __restrict__ out)
{
    __shared__ float wlds[64 * 8];
    const int tid = threadIdx.x;
    const int dc = blockIdx.x, tc = blockIdx.y, b = blockIdx.z;
    const int t0 = tc * 64;

    if (tid < 64) {
        const float* lp = &logits[((size_t)b * T_ + t0 + tid) * E_];
        float ex[8]; float s = 0.f;
        #pragma unroll
        for (int i = 0; i < 8; ++i) { ex[i] = expf(lp[i]); s += ex[i]; }
        const float invs = 1.f / s;
        #pragma unroll
        for (int i = 0; i < 8; ++i) wlds[tid * 8 + i] = ex[i] * invs;
    }
    __syncthreads();

    const int d = dc * 256 + tid;
    float yv[8];
    #pragma unroll
    for (int e = 0; e < 8; ++e) yv[e] = y[(size_t)(b * E_ + e) * D_ + d];

    for (int t = 0; t < 64; ++t) {
        const float4 wA = *(const float4*)&wlds[t * 8];
        const float4 wB = *(const float4*)&wlds[t * 8 + 4];
        const float acc = wA.x*yv[0] + wA.y*yv[1] + wA.z*yv[2] + wA.w*yv[3]
                        + wB.x*yv[4] + wB.y*yv[5] + wB.z*yv[6] + wB.w*yv[7];
        out[((size_t)b * T_ + t0 + t) * D_ + d] = acc;
    }
}

// ---------------------------------------------------------------------------
extern "C" void kernel_launch(void* const* d_in, const int* in_sizes, int n_in,
                              void* d_out, int out_size, void* d_ws, size_t ws_size,
                              hipStream_t stream)
{
    const float* X  = (const float*)d_in[0];
    const float* Wg = (const float*)d_in[1];
    const float* bg = (const float*)d_in[2];
    const float* W1 = (const float*)d_in[3];
    const float* b1 = (const float*)d_in[4];
    const float* W2 = (const float*)d_in[5];
    const float* b2 = (const float*)d_in[6];
    float* out = (float*)d_out;

    // ws (fp32), ~1.9 MB: logits | sexp_part | slots | h | y
    float* wsf       = (float*)d_ws;
    float* logits    = wsf;                        // 131072
    float* sexp_part = logits + BT_ * E_;          // 512
    float* slots     = sexp_part + 512;            // 65536
    float* h         = slots + N_ * D_;            // 262144
    float* y         = h + N_ * FF_;               // 65536

    hipLaunchKernelGGL(k_logits_part,  dim3(BT_ / 256, 8), dim3(256), 0, stream,
                       X, Wg, out);
    hipLaunchKernelGGL(k_logits_merge, dim3(BT_ / 256),    dim3(256), 0, stream,
                       out, bg, logits, sexp_part);
    hipLaunchKernelGGL(k_slots_part,   dim3(64, 8),        dim3(256), 0, stream,
                       X, logits, sexp_part, out);
    hipLaunchKernelGGL(k_reduce_slots, dim3(256),          dim3(256), 0, stream,
                       out, slots);
    hipLaunchKernelGGL((k_ffn<1024, 4096, 2>), dim3(FF_ / 16, 2), dim3(256), 0,
                       stream, slots, W1, out + G1PART_F);
    hipLaunchKernelGGL(k_reduce_silu,  dim3(256), dim3(256), 0, stream,
                       out, b1, h);
    hipLaunchKernelGGL((k_ffn<4096, 1024, 8>), dim3(D_ / 16, 8), dim3(256), 0,
                       stream, h, W2, out + G2PART_F);
    hipLaunchKernelGGL(k_reduce_bias,  dim3(64), dim3(256), 0, stream,
                       out, b2, y);
    hipLaunchKernelGGL(k_combine,      dim3(4, 32, 8), dim3(256), 0, stream,
                       logits, y, out);
}

// Round 9
// 274.367 us; speedup vs baseline: 2.2469x; 1.0361x over previous
//
#include <hip/hip_runtime.h>
#include <math.h>

#define B_  8
#define T_  2048
#define D_  1024
#define E_  8
#define FF_ 4096
#define N_  64            // B*E rows through the FFN
#define BT_ (B_*T_)

// ---- d_out scratch regions (float offsets), all dead before k_combine ----
#define LPART_F  0u           // [8][BT][8]       4 MB (dead after merge)
#define SPART_F  1048576u     // [64][64][1024]  16 MB (slot partials)
#define G1PART_F 5242880u     // [16][64][4096]  16 MB
#define G2PART_F 9437184u     // [64][64][1024]  16 MB

// ---------------------------------------------------------------------------
// K1a: partial logits over a 128-d chunk. grid (BT/256, 8), 256 threads.
// Thread owns ONE token, all 8 experts. X staged in LDS (coalesced);
// Wg read with block-uniform addresses -> scalar s_load path.
// ---------------------------------------------------------------------------
__global__ __launch_bounds__(256) void k_logits_part(
    const float* __restrict__ X, const float* __restrict__ Wg,
    float* __restrict__ part)
{
    __shared__ float xt[256 * 36];       // 256 tokens x 32 d (pad 36), 36 KB

    const int tid = threadIdx.x;
    const int bt0 = blockIdx.x * 256;
    const int d0  = blockIdx.y * 128;

    float acc[8];
    #pragma unroll
    for (int e = 0; e < 8; ++e) acc[e] = 0.f;

    for (int dt = 0; dt < 4; ++dt) {
        if (dt) __syncthreads();          // WAR: previous compute vs restage
        #pragma unroll
        for (int r = 0; r < 8; ++r) {
            int fi = r * 256 + tid;       // float4 index = token*8 + dj
            int token = fi >> 3, dj = fi & 7;
            const float4 v = *(const float4*)
                &X[(size_t)(bt0 + token) * D_ + d0 + dt * 32 + dj * 4];
            *(float4*)&xt[token * 36 + dj * 4] = v;
        }
        __syncthreads();
        #pragma unroll
        for (int dj = 0; dj < 8; ++dj) {
            const float4 x4 = *(const float4*)&xt[tid * 36 + dj * 4];
            const int db = d0 + dt * 32 + dj * 4;      // block-uniform
            const float xv[4] = {x4.x, x4.y, x4.z, x4.w};
            #pragma unroll
            for (int r = 0; r < 4; ++r) {
                const float4 wlo = *(const float4*)&Wg[(size_t)(db + r) * 8];
                const float4 whi = *(const float4*)&Wg[(size_t)(db + r) * 8 + 4];
                acc[0] += xv[r] * wlo.x; acc[1] += xv[r] * wlo.y;
                acc[2] += xv[r] * wlo.z; acc[3] += xv[r] * wlo.w;
                acc[4] += xv[r] * whi.x; acc[5] += xv[r] * whi.y;
                acc[6] += xv[r] * whi.z; acc[7] += xv[r] * whi.w;
            }
        }
    }

    float* pp = &part[LPART_F + (size_t)blockIdx.y * BT_ * E_
                      + (size_t)(bt0 + tid) * E_];
    *(float4*)&pp[0] = make_float4(acc[0], acc[1], acc[2], acc[3]);
    *(float4*)&pp[4] = make_float4(acc[4], acc[5], acc[6], acc[7]);
}

// ---------------------------------------------------------------------------
// K1b: merge 8 d-chunk partials + bg -> logits; per-block per-e sum of exp
// written to sexp_part[blk][8] (no atomics). grid (BT/256) = 64.
// ---------------------------------------------------------------------------
__global__ __launch_bounds__(256) void k_logits_merge(
    const float* __restrict__ part, const float* __restrict__ bg,
    float* __restrict__ logits, float* __restrict__ sexp_part)
{
    __shared__ float red[8 * 256];
    const int tid = threadIdx.x;
    const int token = blockIdx.x * 256 + tid;

    float a[8];
    #pragma unroll
    for (int e = 0; e < 8; ++e) a[e] = 0.f;
    #pragma unroll
    for (int p = 0; p < 8; ++p) {
        const float* pp = &part[LPART_F + (size_t)p * BT_ * E_
                                + (size_t)token * E_];
        const float4 v0 = *(const float4*)&pp[0];
        const float4 v1 = *(const float4*)&pp[4];
        a[0] += v0.x; a[1] += v0.y; a[2] += v0.z; a[3] += v0.w;
        a[4] += v1.x; a[5] += v1.y; a[6] += v1.z; a[7] += v1.w;
    }
    #pragma unroll
    for (int e = 0; e < 8; ++e) a[e] += bg[e];

    float* lp = &logits[(size_t)token * E_];
    *(float4*)&lp[0] = make_float4(a[0], a[1], a[2], a[3]);
    *(float4*)&lp[4] = make_float4(a[4], a[5], a[6], a[7]);

    #pragma unroll
    for (int e = 0; e < 8; ++e) red[e * 256 + tid] = expf(a[e]);
    __syncthreads();
    for (int s = 128; s >= 1; s >>= 1) {
        if (tid < s) {
            #pragma unroll
            for (int e = 0; e < 8; ++e)
                red[e * 256 + tid] += red[e * 256 + tid + s];
        }
        __syncthreads();
    }
    if (tid < 8) sexp_part[blockIdx.x * 8 + tid] = red[tid * 256];
}

// ---------------------------------------------------------------------------
// K2: slots partials. grid (64 slices of 32 tokens, 8 b) = 512 blocks.
// ---------------------------------------------------------------------------
__global__ __launch_bounds__(256) void k_slots_part(
    const float* __restrict__ X, const float* __restrict__ logits,
    const float* __restrict__ sexp_part, float* __restrict__ part)
{
    __shared__ float wlds[32 * 8];
    __shared__ float red[64];
    __shared__ float inv[8];

    const int tid = threadIdx.x;
    const int ts = blockIdx.x, b = blockIdx.y;
    const int t0 = ts * 32;

    if (tid < 64) red[tid] = sexp_part[b * 64 + tid];   // [blk-in-b][e]
    __syncthreads();
    if (tid < 8) {
        float s = 0.f;
        #pragma unroll
        for (int i = 0; i < 8; ++i) s += red[i * 8 + tid];
        inv[tid] = 1.f / s;
    }
    __syncthreads();
    {
        int t = tid >> 3, e = tid & 7;    // 256 threads = 32 tokens x 8 e
        wlds[tid] = expf(logits[((size_t)b * T_ + t0 + t) * E_ + e]) * inv[e];
    }
    __syncthreads();

    float4 acc[8];
    #pragma unroll
    for (int e = 0; e < 8; ++e) acc[e] = make_float4(0.f, 0.f, 0.f, 0.f);

    const float* xb = &X[((size_t)b * T_ + t0) * D_ + tid * 4];
    #pragma unroll 8
    for (int t = 0; t < 32; ++t) {
        const float4 x4 = *(const float4*)&xb[(size_t)t * D_];
        const float4 wA = *(const float4*)&wlds[t * 8];       // broadcast
        const float4 wB = *(const float4*)&wlds[t * 8 + 4];   // broadcast
        const float w[8] = {wA.x, wA.y, wA.z, wA.w, wB.x, wB.y, wB.z, wB.w};
        #pragma unroll
        for (int e = 0; e < 8; ++e) {
            acc[e].x += x4.x * w[e];
            acc[e].y += x4.y * w[e];
            acc[e].z += x4.z * w[e];
            acc[e].w += x4.w * w[e];
        }
    }
    #pragma unroll
    for (int e = 0; e < 8; ++e) {
        *(float4*)&part[SPART_F + (size_t)ts * (N_ * D_)
                        + (size_t)(b * E_ + e) * D_ + tid * 4] = acc[e];
    }
}

// K3: reduce 64 slot partials -> slots[64][1024]. grid 256.
__global__ __launch_bounds__(256) void k_reduce_slots(
    const float* __restrict__ part, float* __restrict__ slots)
{
    const int i = blockIdx.x * 256 + threadIdx.x;     // 65536
    float s = 0.f;
    #pragma unroll
    for (int p = 0; p < 64; ++p)
        s += part[SPART_F + (size_t)p * (N_ * D_) + i];
    slots[i] = s;
}

// ---------------------------------------------------------------------------
// K4/K6: split-K GEMM, K-chunk = 64, grid (F/64, K/64) = 1024 blocks
// (4 blocks/CU, 16 waves/CU). Thread = 4 rows x 4 f (rg=tid>>4, cg=tid&15):
// acc = 4 x float4 = 16 VGPR. A-tile 64x64 staged in LDS (pad 68: 4-row
// broadcast reads are 2-way aliased = free). W reads: 16 distinct float4 =
// 256B contiguous per inst, 4-way lane redundancy (L1-absorbed).
// unroll 4 -> 16 independent W loads in flight per wave -> ~4 KB/CU in
// flight (Little's law => ~2.7 TB/s W streaming, was ~0.5 TB/s in R7).
// part[kc][row][f] written direct (no contention, no atomics).
// ---------------------------------------------------------------------------
template<int K, int F>
__global__ __launch_bounds__(256, 4) void k_ffn(
    const float* __restrict__ A, const float* __restrict__ W,
    float* __restrict__ part)
{
    __shared__ float As[64 * 68];                 // 17.4 KB

    const int tid = threadIdx.x;
    const int rg = tid >> 4;                      // 0..15 (4 rows each)
    const int cg = tid & 15;                      // 0..15 (4 cols each)
    const int f0 = blockIdx.x * 64 + cg * 4;
    const int k0 = blockIdx.y * 64;

    // stage A tile 64 rows x 64 k: 1024 float4, 4 per thread, coalesced.
    #pragma unroll
    for (int i = 0; i < 4; ++i) {
        int idx = i * 256 + tid;
        int row = idx >> 4, kq = idx & 15;
        *(float4*)&As[row * 68 + kq * 4] =
            *(const float4*)&A[(size_t)row * K + k0 + kq * 4];
    }
    __syncthreads();

    float4 acc[4];
    #pragma unroll
    for (int r = 0; r < 4; ++r) acc[r] = make_float4(0.f, 0.f, 0.f, 0.f);

    #pragma unroll 4
    for (int kq = 0; kq < 16; ++kq) {             // 4 k per step
        const float* wr = &W[(size_t)(k0 + kq * 4) * F + f0];
        const float4 w0 = *(const float4*)&wr[0];
        const float4 w1 = *(const float4*)&wr[(size_t)F];
        const float4 w2 = *(const float4*)&wr[2 * (size_t)F];
        const float4 w3 = *(const float4*)&wr[3 * (size_t)F];
        #pragma unroll
        for (int r = 0; r < 4; ++r) {
            const float4 a = *(const float4*)&As[(rg * 4 + r) * 68 + kq * 4];
            acc[r].x += a.x*w0.x + a.y*w1.x + a.z*w2.x + a.w*w3.x;
            acc[r].y += a.x*w0.y + a.y*w1.y + a.z*w2.y + a.w*w3.y;
            acc[r].z += a.x*w0.z + a.y*w1.z + a.z*w2.z + a.w*w3.z;
            acc[r].w += a.x*w0.w + a.y*w1.w + a.z*w2.w + a.w*w3.w;
        }
    }

    float* pb = &part[(size_t)blockIdx.y * (N_ * F)];
    #pragma unroll
    for (int r = 0; r < 4; ++r)
        *(float4*)&pb[(size_t)(rg * 4 + r) * F + f0] = acc[r];
}

// K5: h = silu(sum of 16 gemm1 partials + b1). SCALAR per thread ->
// grid 1024 blocks (full machine), 16 independent loads in flight.
__global__ __launch_bounds__(256) void k_reduce_silu(
    const float* __restrict__ part, const float* __restrict__ b1,
    float* __restrict__ h)
{
    const int i = blockIdx.x * 256 + threadIdx.x;     // 262144
    float s = b1[i & (FF_ - 1)];
    #pragma unroll
    for (int p = 0; p < 16; ++p)
        s += part[G1PART_F + (size_t)p * (N_ * FF_) + i];
    h[i] = s / (1.f + expf(-s));
}

// K7: y = sum of 64 gemm2 partials + b2. SCALAR per thread -> grid 256.
__global__ __launch_bounds__(256) void k_reduce_bias(
    const float* __restrict__ part, const float* __restrict__ b2,
    float* __restrict__ y)
{
    const int i = blockIdx.x * 256 + threadIdx.x;     // 65536
    float s = b2[i & (D_ - 1)];
    #pragma unroll
    for (int p = 0; p < 64; ++p)
        s += part[G2PART_F + (size_t)p * (N_ * D_) + i];
    y[i] = s;
}

// ---------------------------------------------------------------------------
// K8: out[b][t][d] = sum_e softmax_e(logits[b,t,:])[e] * y[b*8+e][d]
// ---------------------------------------------------------------------------
__global__ __launch_bounds__(256) void k_combine(
    const float* __restrict__ logits, const float* __restrict__ y,
    float* __restrict__ out)
{
    __shared__ float wlds[64 * 8];
    const int tid = threadIdx.x;
    const int dc = blockIdx.x, tc = blockIdx.y, b = blockIdx.z;
    const int t0 = tc * 64;

    if (tid < 64) {
        const float* lp = &logits[((size_t)b * T_ + t0 + tid) * E_];
        float ex[8]; float s = 0.f;
        #pragma unroll
        for (int i = 0; i < 8; ++i) { ex[i] = expf(lp[i]); s += ex[i]; }
        const float invs = 1.f / s;
        #pragma unroll
        for (int i = 0; i < 8; ++i) wlds[tid * 8 + i] = ex[i] * invs;
    }
    __syncthreads();

    const int d = dc * 256 + tid;
    float yv[8];
    #pragma unroll
    for (int e = 0; e < 8; ++e) yv[e] = y[(size_t)(b * E_ + e) * D_ + d];

    for (int t = 0; t < 64; ++t) {
        const float4 wA = *(const float4*)&wlds[t * 8];
        const float4 wB = *(const float4*)&wlds[t * 8 + 4];
        const float acc = wA.x*yv[0] + wA.y*yv[1] + wA.z*yv[2] + wA.w*yv[3]
                        + wB.x*yv[4] + wB.y*yv[5] + wB.z*yv[6] + wB.w*yv[7];
        out[((size_t)b * T_ + t0 + t) * D_ + d] = acc;
    }
}

// ---------------------------------------------------------------------------
extern "C" void kernel_launch(void* const* d_in, const int* in_sizes, int n_in,
                              void* d_out, int out_size, void* d_ws, size_t ws_size,
                              hipStream_t stream)
{
    const float* X  = (const float*)d_in[0];
    const float* Wg = (const float*)d_in[1];
    const float* bg = (const float*)d_in[2];
    const float* W1 = (const float*)d_in[3];
    const float* b1 = (const float*)d_in[4];
    const float* W2 = (const float*)d_in[5];
    const float* b2 = (const float*)d_in[6];
    float* out = (float*)d_out;

    // ws (fp32), ~1.9 MB: logits | sexp_part | slots | h | y
    float* wsf       = (float*)d_ws;
    float* logits    = wsf;                        // 131072
    float* sexp_part = logits + BT_ * E_;          // 512
    float* slots     = sexp_part + 512;            // 65536
    float* h         = slots + N_ * D_;            // 262144
    float* y         = h + N_ * FF_;               // 65536

    hipLaunchKernelGGL(k_logits_part,  dim3(BT_ / 256, 8), dim3(256), 0, stream,
                       X, Wg, out);
    hipLaunchKernelGGL(k_logits_merge, dim3(BT_ / 256),    dim3(256), 0, stream,
                       out, bg, logits, sexp_part);
    hipLaunchKernelGGL(k_slots_part,   dim3(64, 8),        dim3(256), 0, stream,
                       X, logits, sexp_part, out);
    hipLaunchKernelGGL(k_reduce_slots, dim3(256),          dim3(256), 0, stream,
                       out, slots);
    hipLaunchKernelGGL((k_ffn<1024, 4096>), dim3(FF_ / 64, 1024 / 64),
                       dim3(256), 0, stream, slots, W1, out + G1PART_F);
    hipLaunchKernelGGL(k_reduce_silu,  dim3(N_ * FF_ / 256), dim3(256), 0, stream,
                       out, b1, h);
    hipLaunchKernelGGL((k_ffn<4096, 1024>), dim3(D_ / 64, FF_ / 64),
                       dim3(256), 0, stream, h, W2, out + G2PART_F);
    hipLaunchKernelGGL(k_reduce_bias,  dim3(N_ * D_ / 256), dim3(256), 0, stream,
                       out, b2, y);
    hipLaunchKernelGGL(k_combine,      dim3(4, 32, 8), dim3(256), 0, stream,
                       logits, y, out);
}